// Round 14
// baseline (294.983 us; speedup 1.0000x reference)
//
#include <hip/hip_runtime.h>

#define DEV __device__ __forceinline__

using f32x4 = __attribute__((ext_vector_type(4))) float;
using f16x8 = __attribute__((ext_vector_type(8))) _Float16;
using f16x4 = __attribute__((ext_vector_type(4))) _Float16;

constexpr int Bc = 8, Tc = 2048, Ec = 1024, Hc = 1024;
constexpr int Mc = Bc * Tc;      // 16384 total rows
constexpr int SLOTA = 128 * 32;  // A slice elems (8KB)
constexpr int SLOTB = 256 * 32;  // B slice elems (16KB)

DEV f32x4 mfma16(f16x8 a, f16x8 b, f32x4 c) {
    return __builtin_amdgcn_mfma_f32_16x16x32_f16(a, b, c, 0, 0, 0);
}
DEV unsigned short f16bits(float f) { return __builtin_bit_cast(unsigned short, (_Float16)f); }
DEV float f16val(unsigned short u) { return (float)__builtin_bit_cast(_Float16, u); }

// async global->LDS, 16B per lane. LDS dest must be wave-uniform base; HW adds lane*16.
DEV void gload16(const _Float16* g, _Float16* l) {
    __builtin_amdgcn_global_load_lds(
        (const __attribute__((address_space(1))) unsigned int*)g,
        (__attribute__((address_space(3))) unsigned int*)l, 16, 0, 0);
}

// Paired-row swizzled LDS slice layout (R x 32 f16):
// LDS row r (128B) holds tile-rows {2r, 2r+1}; the 8 16B slots within row r
// are XOR-permuted by (r&7).  Verified 0 bank conflicts (rounds 5-13).
DEV int swz_off(int R, int lk) {
    return ((R >> 1) << 6) + ((((((R & 1) << 2) | lk) ^ ((R >> 1) & 7))) << 3);
}

// ---------------------------------------------------------------------------
// prep_x: f32 x -> f16
// ---------------------------------------------------------------------------
__global__ __launch_bounds__(256) void prep_x(const float* __restrict__ x,
                                              _Float16* __restrict__ xf, int n) {
    int i = (blockIdx.x * 256 + threadIdx.x) * 4;
    if (i >= n) return;
    f32x4 v = *reinterpret_cast<const f32x4*>(x + i);
    f16x4 h;
#pragma unroll
    for (int j = 0; j < 4; j++) h[j] = (_Float16)v[j];
    *reinterpret_cast<f16x4*>(xf + i) = h;
}

// ---------------------------------------------------------------------------
// prep_w: transpose W[e][n] -> WT[n][e], f16.
// Wall[3072][1024]: rows [0,1024)=Wq, [1024,2048)=Wk, [2048,3072)=Wv.
// ---------------------------------------------------------------------------
__global__ __launch_bounds__(256) void prep_w(const float* __restrict__ wq,
                                              const float* __restrict__ wk,
                                              const float* __restrict__ wv,
                                              _Float16* __restrict__ wall) {
    __shared__ float tile[32][33];
    const int z = blockIdx.z;
    const float* src = (z == 0) ? wq : (z == 1) ? wk : wv;
    _Float16* dh = wall + (size_t)z * 1024 * Ec;
    const int n0 = blockIdx.x * 32, e0 = blockIdx.y * 32;
    const int tx = threadIdx.x & 31, ty = threadIdx.x >> 5;  // 32 x 8
#pragma unroll
    for (int j = 0; j < 32; j += 8)
        tile[ty + j][tx] = src[(size_t)(e0 + ty + j) * Hc + n0 + tx];
    __syncthreads();
#pragma unroll
    for (int j = 0; j < 32; j += 8)
        dh[(size_t)(n0 + ty + j) * Ec + e0 + tx] = (_Float16)tile[tx][ty + j];
}

// ---------------------------------------------------------------------------
// gemm_body: 128x256 tile, 4 waves (1x4, each 128x64), 256 threads, BK=32
// slots, ring-3 LDS (72 KiB -> TWO blocks/CU; 232 unified regs/wave = 2
// waves/SIMD, both fit).  Cross-block overlap (independent barriers) fills
// the per-slot stall that capped 8-wave blocks at 39-46% MfmaUtil.
// Round-10 schedule, ONE barrier per slot:
//   { 12 ds_read (bfr then af); stage(P+2) -> slot (P+2)%3 (6 gloads);
//     setprio(1); 32 MFMA; setprio(0); vmcnt(6); s_barrier }
// Counted vmcnt(6): stage(P+2)'s 6 loads may stay in flight; stage(P+1)
// (issued in slot P-1) is proven complete at the slot exit.
// Per-element K accumulation order identical to round 13 (bit-identical out).
// EPI: 0 = f16 out, N=2048: Q (gn<1024) / K (gn>=1024)
//      1 = f16 transposed store Vt[b][n][t]
//      2 = f16 causal energy * 1/sqrt(dk)
//      3 = f32 row-major (PV), nkt = ((qband>>1)+1)*8
// ---------------------------------------------------------------------------
template <int EPI>
DEV void gemm_body(int bx, int mt, int z,
                   const _Float16* __restrict__ Ah, const _Float16* __restrict__ Bh,
                   void* __restrict__ out0, void* __restrict__ out2,
                   const int* __restrict__ dkp,
                   int lda, int ldb, size_t aBS, size_t bBS, size_t oBS, int nkt,
                   _Float16* sAb, _Float16* sBb) {
    if (EPI == 3) nkt = ((mt >> 1) + 1) * 8;  // causal K extent (qband mt)

    Ah += (size_t)z * aBS;
    Bh += (size_t)z * bBS;

    const float scale = (EPI == 2) ? (1.0f / sqrtf((float)*dkp)) : 1.0f;

    const int tid = threadIdx.x;
    const int wave = tid >> 6, lane = tid & 63;
    const int lr = lane & 15, lk = lane >> 4;
    const int wn = wave;                // 1 x 4 wave grid; wave owns 128 x 64
    const int m0 = mt * 128, n0 = bx * 256;

    // staging constants (inverse-swizzled global source, linear LDS dest):
    const int so = (lane & 7) ^ (lane >> 3);
    const int strow = 2 * (lane >> 3) + (so >> 2);
    const int stcol = (so & 3) * 8;
    // A: 8 16-row groups over 4 waves (2/wave); B: 16 groups (4/wave)
    const size_t aoff0 = (size_t)(m0 + (wave * 2 + 0) * 16 + strow) * lda + stcol;
    const size_t aoff1 = (size_t)(m0 + (wave * 2 + 1) * 16 + strow) * lda + stcol;
    size_t boff[4];
#pragma unroll
    for (int l = 0; l < 4; l++)
        boff[l] = (size_t)(n0 + (wave * 4 + l) * 16 + strow) * ldb + stcol;
    const int lda0 = (wave * 2 + 0) * 512, lda1 = (wave * 2 + 1) * 512;

    auto stage = [&](int sv, int slot) {
        const int kk = sv * 32;
        _Float16* dA = sAb + slot * SLOTA;
        _Float16* dB = sBb + slot * SLOTB;
        gload16(Ah + aoff0 + kk, dA + lda0);
        gload16(Ah + aoff1 + kk, dA + lda1);
#pragma unroll
        for (int l = 0; l < 4; l++)
            gload16(Bh + boff[l] + kk, dB + (wave * 4 + l) * 512);
    };

    f32x4 acc[8][4] = {};

    // prologue: slots 0 and 1 in flight; gate slot 0 (allow slot 1's 6 loads)
    stage(0, 0);
    stage(1, 1);
    asm volatile("s_waitcnt vmcnt(6)" ::: "memory");
    __builtin_amdgcn_s_barrier();

    int rP = 0;  // P % 3
    for (int P = 0; P < nkt; ++P) {
        const _Float16* cA = sAb + rP * SLOTA;
        const _Float16* cB = sBb + rP * SLOTB;
        f16x8 af[8], bfr[4];

        // B frags first so the first MFMA's operands arrive earliest
#pragma unroll
        for (int nj = 0; nj < 4; nj++)
            bfr[nj] = *reinterpret_cast<const f16x8*>(
                &cB[swz_off(wn * 64 + nj * 16 + lr, lk)]);
#pragma unroll
        for (int mi = 0; mi < 8; mi++)
            af[mi] = *reinterpret_cast<const f16x8*>(
                &cA[swz_off(mi * 16 + lr, lk)]);

        int rs = rP + 2; if (rs >= 3) rs -= 3;
        if (P + 2 < nkt) stage(P + 2, rs);

        __builtin_amdgcn_s_setprio(1);
#pragma unroll
        for (int mi = 0; mi < 8; mi++)
#pragma unroll
            for (int nj = 0; nj < 4; nj++)
                acc[mi][nj] = mfma16(af[mi], bfr[nj], acc[mi][nj]);
        __builtin_amdgcn_s_setprio(0);

        // slot-exit gate: stage(P+1) must be complete (counted; never 0 in
        // steady state).  Skip entirely on the last slot.
        if (P + 2 < nkt) {
            asm volatile("s_waitcnt vmcnt(6)" ::: "memory");
            __builtin_amdgcn_s_barrier();
        } else if (P + 1 < nkt) {
            asm volatile("s_waitcnt vmcnt(0)" ::: "memory");
            __builtin_amdgcn_s_barrier();
        }
        if (++rP == 3) rP = 0;
    }

#pragma unroll
    for (int mi = 0; mi < 8; mi++)
#pragma unroll
        for (int nj = 0; nj < 4; nj++) {
            const int gn = n0 + wn * 64 + nj * 16 + lr;
            if (EPI == 1) {
                const int gm0 = m0 + mi * 16 + lk * 4;
                const int bb = gm0 >> 11, t = gm0 & (Tc - 1);
                f16x4 pk;
#pragma unroll
                for (int r = 0; r < 4; r++) pk[r] = (_Float16)acc[mi][nj][r];
                *reinterpret_cast<f16x4*>(
                    &((_Float16*)out0)[((size_t)(bb * Hc + gn)) * Tc + t]) = pk;
            } else if (EPI == 0) {
                _Float16* od = (gn < 1024) ? (_Float16*)out0 : (_Float16*)out2;
                const int cc = gn & 1023;
#pragma unroll
                for (int r = 0; r < 4; r++) {
                    const int gm = m0 + mi * 16 + lk * 4 + r;
                    od[(size_t)gm * Hc + cc] = (_Float16)acc[mi][nj][r];
                }
            } else {
#pragma unroll
                for (int r = 0; r < 4; r++) {
                    const int gm = m0 + mi * 16 + lk * 4 + r;
                    const float v = acc[mi][nj][r];
                    if (EPI == 2) {
                        const float e = (gn > gm) ? -INFINITY : v * scale;
                        ((unsigned short*)out0)[(size_t)z * oBS + (size_t)gm * Tc + gn] =
                            f16bits(e);
                    } else {
                        ((float*)out0)[(size_t)z * oBS + (size_t)gm * Hc + gn] = v;
                    }
                }
            }
        }
}

// ---------------------------------------------------------------------------
// k_qkv: QK-projection (1024 blocks: 128 m-tiles x 8 bx) + V-projection
// (512 blocks: 128 x 4), all 32 slots.  2 blocks/CU -> 3 rounds of 512.
// launch_bounds(256,2): cap 256 regs/wave (need ~232; (512,4)-style
// over-tightening spilled acc in round 8 — do not lower).
// ---------------------------------------------------------------------------
__global__ __launch_bounds__(256, 2) void k_qkv(
        const _Float16* __restrict__ Xf, const _Float16* __restrict__ Wall,
        _Float16* __restrict__ Qf, _Float16* __restrict__ Kf,
        _Float16* __restrict__ Vt, const int* __restrict__ dkp) {
    __shared__ _Float16 sA[3][SLOTA];  // 24 KiB
    __shared__ _Float16 sB[3][SLOTB];  // 48 KiB
    const int i = blockIdx.x;
    if (i < 1024) {
        // QK proj: bijective XCD chunking over the 1024-block tile grid
        const int w = (i & 7) * 128 + (i >> 3);
        const int mt = w >> 3, bx = w & 7;
        gemm_body<0>(bx, mt, 0, Xf, Wall, Qf, Kf, dkp,
                     Ec, Ec, 0, 0, 0, 32, sA[0], sB[0]);
    } else {
        const int j = i - 1024;  // V proj: (4 bx x 128 mt) grid
        gemm_body<1>(j & 3, j >> 2, 0, Xf, Wall + (size_t)2048 * Ec,
                     Vt, nullptr, dkp, Ec, Ec, 0, 0, 0, 32, sA[0], sB[0]);
    }
}

// ---------------------------------------------------------------------------
// k_energy: 576 causal tiles (72 per batch: qband i has (i>>1)+1 k-tiles),
// 32 slots each; ~1.1 rounds at 2 blocks/CU.
// ---------------------------------------------------------------------------
__global__ __launch_bounds__(256, 2) void k_energy(
        const _Float16* __restrict__ Qf, const _Float16* __restrict__ Kf,
        unsigned short* __restrict__ S, const int* __restrict__ dkp) {
    __shared__ _Float16 sA[3][SLOTA];
    __shared__ _Float16 sB[3][SLOTB];
    const int i = blockIdx.x;
    const int b = i / 72;
    int t = i - b * 72;
    int qb = 0;
    while (t >= (qb >> 1) + 1) { t -= (qb >> 1) + 1; qb++; }  // k-tile t <= qb>>1
    gemm_body<2>(t, qb, b, Qf, Kf, S, nullptr, dkp,
                 Hc, Hc, (size_t)Tc * Hc, (size_t)Tc * Hc, (size_t)Tc * Tc, 32,
                 sA[0], sB[0]);
}

// ---------------------------------------------------------------------------
// k_pv: 512 blocks (8 batches x 16 qbands x 4 bx), nkt = ((qb>>1)+1)*8.
// qbands enumerated in complementary pairs (qb, 15-qb) so co-resident block
// pairs sum to a constant 72 slots.
// ---------------------------------------------------------------------------
__global__ __launch_bounds__(256, 2) void k_pv(
        const _Float16* __restrict__ S, const _Float16* __restrict__ Vt,
        float* __restrict__ out, const int* __restrict__ dkp) {
    __shared__ _Float16 sA[3][SLOTA];
    __shared__ _Float16 sB[3][SLOTB];
    const int lin = blockIdx.x;
    const int b = lin >> 6;
    const int r = lin & 63;
    const int bx = r & 3, half = (r >> 2) & 1, pp = r >> 3;
    const int qb = half ? 15 - pp : pp;
    gemm_body<3>(bx, qb, b, S, Vt, out, nullptr, dkp,
                 Tc, Tc, (size_t)Tc * Tc, (size_t)Hc * Tc, (size_t)Tc * Hc, 0,
                 sA[0], sB[0]);
}

// ---------------------------------------------------------------------------
// softmax_k: one block per (b,q) row.  f16 logits in, f16 P out (in place).
// Threads beyond the tile-aligned causal extent skip loads/stores (PV never
// reads those cols) but participate in reductions.
// ---------------------------------------------------------------------------
__global__ __launch_bounds__(256) void softmax_k(unsigned short* __restrict__ S) {
    const int q = blockIdx.x & (Tc - 1);
    const int b = blockIdx.x >> 11;
    const int tid = threadIdx.x;
    const int c0 = tid * 8;
    const int limit = ((q >> 8) + 1) << 8;  // tile-aligned causal extent
    const bool active = c0 < limit;
    unsigned short* row = S + ((size_t)b * Tc + q) * Tc;

    float v[8];
    if (active) {
        uint4 raw = *reinterpret_cast<const uint4*>(row + c0);
        unsigned u[4] = {raw.x, raw.y, raw.z, raw.w};
#pragma unroll
        for (int p = 0; p < 4; p++) {
            v[2 * p]     = f16val((unsigned short)(u[p] & 0xFFFFu));
            v[2 * p + 1] = f16val((unsigned short)(u[p] >> 16));
        }
#pragma unroll
        for (int i = 0; i < 8; i++)
            if (c0 + i > q) v[i] = -INFINITY;
    } else {
#pragma unroll
        for (int i = 0; i < 8; i++) v[i] = -INFINITY;
    }

    float m = v[0];
#pragma unroll
    for (int i = 1; i < 8; i++) m = fmaxf(m, v[i]);
#pragma unroll
    for (int off = 1; off < 64; off <<= 1) m = fmaxf(m, __shfl_xor(m, off));
    __shared__ float red[4];
    if ((tid & 63) == 0) red[tid >> 6] = m;
    __syncthreads();
    m = fmaxf(fmaxf(red[0], red[1]), fmaxf(red[2], red[3]));

    float e[8], s = 0.f;
#pragma unroll
    for (int i = 0; i < 8; i++) {
        e[i] = __expf(v[i] - m);  // exp(-inf)=0
        s += e[i];
    }
#pragma unroll
    for (int off = 1; off < 64; off <<= 1) s += __shfl_xor(s, off);
    __syncthreads();
    if ((tid & 63) == 0) red[tid >> 6] = s;
    __syncthreads();
    s = red[0] + red[1] + red[2] + red[3];
    const float inv = 1.0f / s;

    if (active) {
        unsigned o[4];
#pragma unroll
        for (int p = 0; p < 4; p++) {
            unsigned short a = f16bits(e[2 * p] * inv);
            unsigned short bb = f16bits(e[2 * p + 1] * inv);
            o[p] = (unsigned)a | ((unsigned)bb << 16);
        }
        uint4 w; w.x = o[0]; w.y = o[1]; w.z = o[2]; w.w = o[3];
        *reinterpret_cast<uint4*>(row + c0) = w;
    }
}

// ---------------------------------------------------------------------------
extern "C" void kernel_launch(void* const* d_in, const int* in_sizes, int n_in,
                              void* d_out, int out_size, void* d_ws, size_t ws_size,
                              hipStream_t stream) {
    const float* x  = (const float*)d_in[0];
    const float* Wq = (const float*)d_in[1];
    const float* Wk = (const float*)d_in[2];
    const float* Wv = (const float*)d_in[3];
    const int*   dk = (const int*)d_in[4];
    float* out = (float*)d_out;
    char* ws = (char*)d_ws;

    const size_t SZ_XE = (size_t)Mc * Ec * 2;  // 32 MiB (f16 [16384][1024])
    const size_t SZ_W  = (size_t)Ec * Hc * 2;  // 2 MiB

    // Layout: persistent buffers first, prep buffers last so S can alias them.
    size_t o = 0;
    auto nxt = [&](size_t bytes) { void* p = ws + o; o += bytes; return p; };
    _Float16* Qf   = (_Float16*)nxt(SZ_XE);
    _Float16* Kf   = (_Float16*)nxt(SZ_XE);
    _Float16* Vt   = (_Float16*)nxt(SZ_XE);
    _Float16* Xf   = (_Float16*)nxt(SZ_XE);
    _Float16* Wall = (_Float16*)nxt(3 * SZ_W);  // [3072][1024] = Wq|Wk|Wv, transposed
    // S: all-batch f16 [8][2048][2048] = 64 MiB, aliases Xf+Wall+beyond
    // (Xf and Wall are dead once k_qkv completes; k_energy is stream-ordered).
    unsigned short* S = (unsigned short*)Xf;
    (void)ws_size; (void)in_sizes; (void)n_in; (void)out_size;

    prep_x<<<(Mc * Ec / 4 + 255) / 256, 256, 0, stream>>>(x, Xf, Mc * Ec);
    prep_w<<<dim3(32, 32, 3), 256, 0, stream>>>(Wq, Wk, Wv, Wall);

    // Q, K, V projections: single-term f16, K=1024
    k_qkv<<<1536, 256, 0, stream>>>(Xf, Wall, Qf, Kf, Vt, dk);

    // energy: 576 causal tiles, f16 logits
    k_energy<<<576, 256, 0, stream>>>(Qf, Kf, (unsigned short*)S, dk);

    softmax_k<<<Bc * Tc, 256, 0, stream>>>((unsigned short*)S);

    // PV: complementary-paired qbands, nkt=((qb>>1)+1)*8
    k_pv<<<512, 256, 0, stream>>>((const _Float16*)S, Vt, out, dk);
}